// Round 2
// baseline (925.222 us; speedup 1.0000x reference)
//
#include <hip/hip_runtime.h>
#include <hip/hip_bf16.h>

// Fused Comm_OUT pipeline, batch-row-parallel (GRU recurrence is per-row).
// Round-9: device-BW attack. r8 evidence: 2x occupancy + -24% per-wave tx
// -> 0% dur change; FETCH doubled to 928MB (1.8 TB/s beyond-L2) with a
// 400KB hot set -> weight broadcast is served from L3 at a shared-BW
// limit that accounts for ~100% of runtime. Lever: halve device-wide
// weight traffic with BM=64 / 128 blocks (each block reads Whh once per
// step regardless of BM; compute pipes have 5x headroom). Half the CUs
// idle BY DESIGN - discriminates shared-BW vs per-CU bound.
// VGPR fit at 16 waves (128 cap): gi r/z packed bf16 (slope<=0.25 damps),
// h carried bf16 (== hb value, zero new error), y recomputed at store,
// gh loop kk-outer/g-inner (A-frag read once per kk). Wc streamed again.
// 128 blocks x 1024 threads (16 waves x 16 cols), BM=64.
// Runtime dtype detection (inputs fp32 or bf16) via g_flag.

typedef __attribute__((ext_vector_type(8))) short bf16x8;   // 8 x bf16 (4 VGPRs)
typedef __attribute__((ext_vector_type(4))) float f32x4;    // MFMA accumulator

#define MFMA16(a, b, c) __builtin_amdgcn_mfma_f32_16x16x32_bf16((a), (b), (c), 0, 0, 0)

constexpr int F   = 640;
constexpr int H   = 256;
constexpr int LSTEPS = 20;
constexpr int CO  = 32;
constexpr int LDP = 264;   // padded bf16 row stride (16B-aligned rows)
constexpr int BM  = 64;    // rows per block

// packed-weight element offsets inside g_wpk (layout unchanged from r7/r8)
constexpr size_t WHH_E  = 0;                    // 8cg*3g*8kk*2j*64lane*8 = 196608
constexpr size_t WIH_E  = 196608;               // 196608
constexpr size_t WC_E   = 393216;               // 8cg*8kk*2j*64*8       = 65536
constexpr size_t WMU_E  = 458752;               // 2w*8kk*64*8           = 8192
constexpr size_t WLIN_E = 466944;               // 8cg*20kk*2j*64*8      = 163840
constexpr size_t PK_ELEMS = 630784;

__device__ __align__(16) unsigned short g_wpk[PK_ELEMS];
__device__ int g_flag;     // 1 = inputs are fp32

__device__ __forceinline__ float bf2f(__hip_bfloat16 x) { return __bfloat162float(x); }
__device__ __forceinline__ float bfu(unsigned short s) {
    __hip_bfloat16 h = *reinterpret_cast<__hip_bfloat16*>(&s);
    return __bfloat162float(h);
}
__device__ __forceinline__ unsigned short f2bs(float f) {
    __hip_bfloat16 h = __float2bfloat16(f);
    return *reinterpret_cast<unsigned short*>(&h);
}
__device__ __forceinline__ bf16x8 lds8(const unsigned short* p) {
    return *reinterpret_cast<const bf16x8*>(p);
}
__device__ __forceinline__ bf16x8 pk8(size_t eoff) {
    return *reinterpret_cast<const bf16x8*>(g_wpk + eoff);
}
__device__ __forceinline__ float sigm(float x) {
    return 1.0f / (1.0f + __expf(-x));
}
__device__ __forceinline__ unsigned pack2(float lo, float hi) {
    return (unsigned)f2bs(lo) | ((unsigned)f2bs(hi) << 16);
}

template<bool F32>
__device__ __forceinline__ bf16x8 g8(const void* base, size_t off) {
    if constexpr (!F32) {
        return *reinterpret_cast<const bf16x8*>((const __hip_bfloat16*)base + off);
    } else {
        const float* f = (const float*)base + off;
        float4 lo = *reinterpret_cast<const float4*>(f);
        float4 hi = *reinterpret_cast<const float4*>(f + 4);
        bf16x8 r;
        r[0] = (short)f2bs(lo.x); r[1] = (short)f2bs(lo.y);
        r[2] = (short)f2bs(lo.z); r[3] = (short)f2bs(lo.w);
        r[4] = (short)f2bs(hi.x); r[5] = (short)f2bs(hi.y);
        r[6] = (short)f2bs(hi.z); r[7] = (short)f2bs(hi.w);
        return r;
    }
}

template<bool F32>
__device__ __forceinline__ float ld1(const void* base, int i) {
    if constexpr (!F32) return bf2f(((const __hip_bfloat16*)base)[i]);
    else                return ((const float*)base)[i];
}

// ---------------- dtype detect: v1 (uniform[0.5,1.5]) ----------------
__global__ void detect_dtype(const void* v1) {
    const unsigned short* u = (const unsigned short*)v1;
    int f32 = 0;
    for (int i = 0; i < 8; ++i) {
        unsigned short s = u[i];
        __hip_bfloat16 h = *reinterpret_cast<__hip_bfloat16*>(&s);
        float v = __bfloat162float(h);
        if (!(v >= 0.25f && v <= 2.0f)) f32 = 1;
    }
    g_flag = f32;
}

// ---------------- weight pre-pack (fp32|bf16 -> bf16 fragment streams) ----------------
__device__ __forceinline__ unsigned short cvt1(const void* p, size_t i, bool f32) {
    if (f32) return f2bs(((const float*)p)[i]);
    return ((const unsigned short*)p)[i];
}

__global__ void prepack(const void* Wlin, const void* Wih, const void* Whh,
                        const void* Wc, const void* Wmu) {
    const bool f32 = (g_flag != 0);
    const int gid = blockIdx.x * 256 + threadIdx.x;
    const void* src;
    size_t dbase;
    int row, col0, ncols;
    if (gid < 24576) {                       // Whh [768,256]
        int idx = gid;
        int lane = idx & 63, j = (idx >> 6) & 1, kk = (idx >> 7) & 7;
        int t2 = idx >> 10, g = t2 % 3, w = t2 / 3;
        row = g * 256 + w * 32 + j * 16 + (lane & 15);
        col0 = kk * 32 + (lane >> 4) * 8;
        ncols = 256; src = Whh; dbase = WHH_E + (size_t)idx * 8;
    } else if (gid < 49152) {                // Wih [768,256]
        int idx = gid - 24576;
        int lane = idx & 63, j = (idx >> 6) & 1, kk = (idx >> 7) & 7;
        int t2 = idx >> 10, g = t2 % 3, w = t2 / 3;
        row = g * 256 + w * 32 + j * 16 + (lane & 15);
        col0 = kk * 32 + (lane >> 4) * 8;
        ncols = 256; src = Wih; dbase = WIH_E + (size_t)idx * 8;
    } else if (gid < 57344) {                // Wc [256,256]
        int idx = gid - 49152;
        int lane = idx & 63, j = (idx >> 6) & 1, kk = (idx >> 7) & 7, w = idx >> 10;
        row = w * 32 + j * 16 + (lane & 15);
        col0 = kk * 32 + (lane >> 4) * 8;
        ncols = 256; src = Wc; dbase = WC_E + (size_t)idx * 8;
    } else if (gid < 58368) {                // Wmu [32,256]
        int idx = gid - 57344;
        int lane = idx & 63, kk = (idx >> 6) & 7, w = idx >> 9;
        row = w * 16 + (lane & 15);
        col0 = kk * 32 + (lane >> 4) * 8;
        ncols = 256; src = Wmu; dbase = WMU_E + (size_t)idx * 8;
    } else if (gid < 78848) {                // Wlin [256,640]
        int idx = gid - 58368;
        int lane = idx & 63, j = (idx >> 6) & 1;
        int t1 = idx >> 7, kk = t1 % 20, w = t1 / 20;
        row = w * 32 + j * 16 + (lane & 15);
        col0 = kk * 32 + (lane >> 4) * 8;
        ncols = 640; src = Wlin; dbase = WLIN_E + (size_t)idx * 8;
    } else {
        return;
    }
    const size_t s0 = (size_t)row * ncols + col0;
    #pragma unroll
    for (int i = 0; i < 8; ++i) g_wpk[dbase + i] = cvt1(src, s0 + i, f32);
}

// ---------------- FAST PATH: BM=64, 1024 threads, 16 waves, 16 cols/wave, 4 m-tiles ----------------
template<bool F32>
__device__ __forceinline__ void fast_pipe(
    const void* hw, const void* blin,
    const void* g1, const void* be1, const void* m1, const void* v1, const void* a1,
    const void* bih, const void* bhh,
    const void* g2, const void* be2, const void* m2, const void* v2, const void* a2,
    const void* bc,
    const void* g3, const void* be3, const void* m3, const void* v3, const void* a3,
    const void* bmu,
    void* out,
    unsigned short* hb, unsigned short* yb, unsigned short* zb)
{
    const int tid  = threadIdx.x;
    const int cg   = tid >> 6;        // wave = 16-col group, 0..15
    const int cgo  = cg >> 1;         // packed-layout 32-col group
    const int jj   = cg & 1;          // 16-col half inside cgo
    const int lane = tid & 63;
    const int m16  = lane & 15;
    const int q    = lane >> 4;
    const int row0 = blockIdx.x * BM;
    const int c0   = cg * 16 + m16;   // this lane's output column
    const size_t lane8 = (size_t)lane * 8;

    // persistent per-step params (folded), scalar per lane
    float s2v, t2v, s3v, t3f, bhhn;
    {
        float s;
        s = ld1<F32>(g2, c0) * rsqrtf(ld1<F32>(v2, c0) + 1e-5f);
        s2v = s; t2v = ld1<F32>(be2, c0) - ld1<F32>(m2, c0) * s;
        s = ld1<F32>(g3, c0) * rsqrtf(ld1<F32>(v3, c0) + 1e-5f);
        s3v = s;
        t3f = (ld1<F32>(bc, c0) - ld1<F32>(m3, c0)) * s + ld1<F32>(be3, c0);
        bhhn = ld1<F32>(bhh, 2 * H + c0);
    }
    const float a2v = ld1<F32>(a2, 0), a3v = ld1<F32>(a3, 0);

    // ---- Phase 1: x = prelu(bn1(rows @ Wlin^T + blin)) -> yb ----
    {
        f32x4 xacc[4] = {};   // [mt]
        #pragma unroll 5
        for (int kk = 0; kk < F / 32; ++kk) {
            bf16x8 b0 = pk8(WLIN_E + (size_t)((cgo * 20 + kk) * 2 + jj) * 512 + lane8);
            #pragma unroll
            for (int mt = 0; mt < 4; ++mt) {
                bf16x8 fa = g8<F32>(hw, (size_t)(row0 + mt * 16 + m16) * F + kk * 32 + q * 8);
                xacc[mt] = MFMA16(fa, b0, xacc[mt]);
            }
        }
        float s = ld1<F32>(g1, c0) * rsqrtf(ld1<F32>(v1, c0) + 1e-5f);
        float t = ld1<F32>(be1, c0) - ld1<F32>(m1, c0) * s;
        float bl = ld1<F32>(blin, c0);
        float av = ld1<F32>(a1, 0);
        #pragma unroll
        for (int mt = 0; mt < 4; ++mt)
            #pragma unroll
            for (int r = 0; r < 4; ++r) {
                float vv = (xacc[mt][r] + bl) * s + t;
                vv = (vv >= 0.0f) ? vv : av * vv;
                yb[(mt * 16 + q * 4 + r) * LDP + c0] = f2bs(vv);
            }
    }
    __syncthreads();   // x visible in yb

    // ---- Phase 2: gi = x @ Wih^T + biases; r/z packed bf16, n kept f32 ----
    unsigned girz[4][4];      // [mt][r]: lo = r-gate pre-act, hi = z-gate pre-act
    f32x4 gin[4];             // [mt]: n-gate pre-act (f32, tanh slope 1)
    {
        f32x4 ga[4][3] = {};  // transient accumulators
        #pragma unroll
        for (int kk = 0; kk < 8; ++kk) {
            bf16x8 b0 = pk8(WIH_E + (size_t)(((cgo * 3 + 0) * 8 + kk) * 2 + jj) * 512 + lane8);
            bf16x8 b1 = pk8(WIH_E + (size_t)(((cgo * 3 + 1) * 8 + kk) * 2 + jj) * 512 + lane8);
            bf16x8 b2 = pk8(WIH_E + (size_t)(((cgo * 3 + 2) * 8 + kk) * 2 + jj) * 512 + lane8);
            #pragma unroll
            for (int mt = 0; mt < 4; ++mt) {
                bf16x8 fa = lds8(yb + (mt * 16 + m16) * LDP + q * 8 + kk * 32);
                ga[mt][0] = MFMA16(fa, b0, ga[mt][0]);
                ga[mt][1] = MFMA16(fa, b1, ga[mt][1]);
                ga[mt][2] = MFMA16(fa, b2, ga[mt][2]);
            }
        }
        const float br = ld1<F32>(bih, 0 * H + c0) + ld1<F32>(bhh, 0 * H + c0);
        const float bz = ld1<F32>(bih, 1 * H + c0) + ld1<F32>(bhh, 1 * H + c0);
        const float bn = ld1<F32>(bih, 2 * H + c0);
        #pragma unroll
        for (int mt = 0; mt < 4; ++mt) {
            #pragma unroll
            for (int r = 0; r < 4; ++r)
                girz[mt][r] = pack2(ga[mt][0][r] + br, ga[mt][1][r] + bz);
            #pragma unroll
            for (int r = 0; r < 4; ++r) gin[mt][r] = ga[mt][2][r] + bn;
        }
    }

    // ---- GRU loop + fused downstream ----
    // Per step t: [gh reads hb(t-1)] [gates] A [write hb,yb] B1
    //             [Wc reads yb -> zb] B2 [Wmu reads zb -> out]
    unsigned short hs[4][4];   // h carried as bf16 (identical to hb contents)
    #pragma unroll
    for (int mt = 0; mt < 4; ++mt)
        #pragma unroll
        for (int r = 0; r < 4; ++r) hs[mt][r] = 0;   // bf16 +0.0

    const unsigned short* haB = hb + m16 * LDP + q * 8;
    const unsigned short* yaB = yb + m16 * LDP + q * 8;
    const int mto = cg >> 1;      // 0..3 (waves 0..7 do Wmu tiles)
    const int nto = cg & 1;
    const unsigned short* zaP = zb + (mto * 16 + m16) * LDP + q * 8;
    const float bmuv = (cg < 8) ? ld1<F32>(bmu, nto * 16 + m16) : 0.0f;

    #pragma unroll 1
    for (int t = 0; t < LSTEPS; ++t) {
        f32x4 gh[4][3] = {};
        if (t > 0) {
            #pragma unroll
            for (int kk = 0; kk < 8; ++kk) {
                bf16x8 b0 = pk8(WHH_E + (size_t)(((cgo * 3 + 0) * 8 + kk) * 2 + jj) * 512 + lane8);
                bf16x8 b1 = pk8(WHH_E + (size_t)(((cgo * 3 + 1) * 8 + kk) * 2 + jj) * 512 + lane8);
                bf16x8 b2 = pk8(WHH_E + (size_t)(((cgo * 3 + 2) * 8 + kk) * 2 + jj) * 512 + lane8);
                #pragma unroll
                for (int mt = 0; mt < 4; ++mt) {
                    bf16x8 fa = lds8(haB + mt * 16 * LDP + kk * 32);
                    gh[mt][0] = MFMA16(fa, b0, gh[mt][0]);
                    gh[mt][1] = MFMA16(fa, b1, gh[mt][1]);
                    gh[mt][2] = MFMA16(fa, b2, gh[mt][2]);
                }
            }
        }
        // gates + h update (h kept bf16, consistent with hb)
        #pragma unroll
        for (int mt = 0; mt < 4; ++mt)
            #pragma unroll
            for (int r = 0; r < 4; ++r) {
                unsigned u = girz[mt][r];
                float rr = sigm(bfu((unsigned short)(u & 0xffffu)) + gh[mt][0][r]);
                float zz = sigm(bfu((unsigned short)(u >> 16)) + gh[mt][1][r]);
                float nin = gin[mt][r] + rr * (gh[mt][2][r] + bhhn);
                float nn = 2.0f * sigm(2.0f * nin) - 1.0f;   // tanh
                float hh = (1.0f - zz) * nn + zz * bfu(hs[mt][r]);
                hs[mt][r] = f2bs(hh);
            }
        __syncthreads();   // A: all reads of hb/yb/zb from prior phases done
        #pragma unroll
        for (int mt = 0; mt < 4; ++mt)
            #pragma unroll
            for (int r = 0; r < 4; ++r) {
                const int idx = (mt * 16 + q * 4 + r) * LDP + c0;
                unsigned short hv = hs[mt][r];
                hb[idx] = hv;
                float y = bfu(hv) * s2v + t2v;           // y recomputed (no yv regs)
                y = (y >= 0.0f) ? y : a2v * y;
                yb[idx] = f2bs(y);
            }
        __syncthreads();   // B1: h/y visible

        // w2 = y @ Wc^T -> z -> zb  (Wc streamed, read once per block per step)
        f32x4 w2[4] = {};
        #pragma unroll
        for (int kk = 0; kk < 8; ++kk) {
            bf16x8 bw = pk8(WC_E + (size_t)((cgo * 8 + kk) * 2 + jj) * 512 + lane8);
            #pragma unroll
            for (int mt = 0; mt < 4; ++mt) {
                bf16x8 fa = lds8(yaB + mt * 16 * LDP + kk * 32);
                w2[mt] = MFMA16(fa, bw, w2[mt]);
            }
        }
        #pragma unroll
        for (int mt = 0; mt < 4; ++mt)
            #pragma unroll
            for (int r = 0; r < 4; ++r) {
                float z0 = w2[mt][r] * s3v + t3f;
                z0 = (z0 >= 0.0f) ? z0 : a3v * z0;
                zb[(mt * 16 + q * 4 + r) * LDP + c0] = f2bs(z0);
            }
        __syncthreads();   // B2: z visible

        // out_t = z @ Wmu^T + bmu   (waves 0..7 own the eight 16x16 tiles)
        if (cg < 8) {
            f32x4 o = {};
            #pragma unroll
            for (int kk = 0; kk < 8; ++kk) {
                bf16x8 a = lds8(zaP + kk * 32);
                bf16x8 b = pk8(WMU_E + (size_t)(nto * 8 + kk) * 512 + lane8);
                o = MFMA16(a, b, o);
            }
            #pragma unroll
            for (int r = 0; r < 4; ++r) {
                float vv = o[r] + bmuv;
                const size_t oi = (size_t)(row0 + mto * 16 + q * 4 + r) * (LSTEPS * CO)
                                + t * CO + nto * 16 + m16;
                if constexpr (F32) ((float*)out)[oi] = vv;
                else               ((__hip_bfloat16*)out)[oi] = __float2bfloat16(vv);
            }
        }
        // safe: zb rewritten only after B2(t+1); hb/yb rewritten only after A(t+1)
    }
}

__global__ __launch_bounds__(1024, 4) void comm_fast(
    const void* hw, const void* blin,
    const void* g1, const void* be1, const void* m1, const void* v1, const void* a1,
    const void* bih, const void* bhh,
    const void* g2, const void* be2, const void* m2, const void* v2, const void* a2,
    const void* bc,
    const void* g3, const void* be3, const void* m3, const void* v3, const void* a3,
    const void* bmu,
    void* out)
{
    __shared__ __align__(16) unsigned short hb[BM * LDP];
    __shared__ __align__(16) unsigned short yb[BM * LDP];
    __shared__ __align__(16) unsigned short zb[BM * LDP];
    if (g_flag) {
        fast_pipe<true >(hw, blin, g1, be1, m1, v1, a1, bih, bhh,
                         g2, be2, m2, v2, a2, bc, g3, be3, m3, v3, a3, bmu,
                         out, hb, yb, zb);
    } else {
        fast_pipe<false>(hw, blin, g1, be1, m1, v1, a1, bih, bhh,
                         g2, be2, m2, v2, a2, bc, g3, be3, m3, v3, a3, bmu,
                         out, hb, yb, zb);
    }
}

extern "C" void kernel_launch(void* const* d_in, const int* in_sizes, int n_in,
                              void* d_out, int out_size, void* d_ws, size_t ws_size,
                              hipStream_t stream) {
    (void)in_sizes; (void)n_in; (void)out_size; (void)d_ws; (void)ws_size;
    detect_dtype<<<dim3(1), dim3(1), 0, stream>>>(d_in[6]);
    prepack<<<dim3(308), dim3(256), 0, stream>>>(
        d_in[1], d_in[8], d_in[9], d_in[17], d_in[24]);
    comm_fast<<<dim3(128), dim3(1024), 0, stream>>>(
        d_in[0], d_in[2],
        d_in[3], d_in[4], d_in[5], d_in[6], d_in[7],
        d_in[10], d_in[11],
        d_in[12], d_in[13], d_in[14], d_in[15], d_in[16],
        d_in[18],
        d_in[19], d_in[20], d_in[21], d_in[22], d_in[23],
        d_in[25],
        d_out);
}

// Round 3
// 553.226 us; speedup vs baseline: 1.6724x; 1.6724x over previous
//
#include <hip/hip_runtime.h>
#include <hip/hip_bf16.h>

// Fused Comm_OUT pipeline, batch-row-parallel (GRU recurrence is per-row).
// Round-10: barrier-convoy attack. Evidence r0-r2: dur insensitive to
// occupancy (r1: 2x waves, flat), insensitive to device BW (r2: -33%
// FETCH, 1.63x WORSE with half the blocks), MFMA/VALU/LDS pipes all at
// <20%. Step time ~61k cyc/CU vs ~5k cyc of issue work -> the 3
// syncthreads/step each force a full vmcnt(0)+lgkmcnt(0) drain; the 4
// barrier-locked mini-phases serialize load latency 3x per step.
// Change: ONE barrier per step. Double-buffer hb/yb/zb by step parity;
// software-pipeline Wc (consumes y(t-1)) and Wmu (consumes z(t-2)) into
// the same scheduling region as gh(t) -> their load streams overlap.
// 512 thr / __launch_bounds__(512,2) -> 256-VGPR cap for deep load ILP
// (r1/r2's VGPR=64 showed the compiler rematerializing under the 128 cap).
// 256 blocks x 512 threads (8 waves x 32 cols), BM=32.
// Runtime dtype detection (inputs fp32 or bf16) via g_flag.

typedef __attribute__((ext_vector_type(8))) short bf16x8;   // 8 x bf16 (4 VGPRs)
typedef __attribute__((ext_vector_type(4))) float f32x4;    // MFMA accumulator

#define MFMA16(a, b, c) __builtin_amdgcn_mfma_f32_16x16x32_bf16((a), (b), (c), 0, 0, 0)

constexpr int F   = 640;
constexpr int H   = 256;
constexpr int LSTEPS = 20;
constexpr int CO  = 32;
constexpr int LDP = 264;   // padded bf16 row stride (16B-aligned rows)
constexpr int BM  = 32;    // rows per block

// packed-weight element offsets inside g_wpk (layout unchanged from r7)
constexpr size_t WHH_E  = 0;                    // 8cg*3g*8kk*2j*64lane*8 = 196608
constexpr size_t WIH_E  = 196608;               // 196608
constexpr size_t WC_E   = 393216;               // 8cg*8kk*2j*64*8       = 65536
constexpr size_t WMU_E  = 458752;               // 2w*8kk*64*8           = 8192
constexpr size_t WLIN_E = 466944;               // 8cg*20kk*2j*64*8      = 163840
constexpr size_t PK_ELEMS = 630784;

__device__ __align__(16) unsigned short g_wpk[PK_ELEMS];
__device__ int g_flag;     // 1 = inputs are fp32

__device__ __forceinline__ float bf2f(__hip_bfloat16 x) { return __bfloat162float(x); }
__device__ __forceinline__ float bfu(unsigned short s) {
    __hip_bfloat16 h = *reinterpret_cast<__hip_bfloat16*>(&s);
    return __bfloat162float(h);
}
__device__ __forceinline__ unsigned short f2bs(float f) {
    __hip_bfloat16 h = __float2bfloat16(f);
    return *reinterpret_cast<unsigned short*>(&h);
}
__device__ __forceinline__ bf16x8 lds8(const unsigned short* p) {
    return *reinterpret_cast<const bf16x8*>(p);
}
__device__ __forceinline__ bf16x8 pk8(size_t eoff) {
    return *reinterpret_cast<const bf16x8*>(g_wpk + eoff);
}
__device__ __forceinline__ float sigm(float x) {
    return 1.0f / (1.0f + __expf(-x));
}
__device__ __forceinline__ unsigned pack2(float lo, float hi) {
    return (unsigned)f2bs(lo) | ((unsigned)f2bs(hi) << 16);
}

template<bool F32>
__device__ __forceinline__ bf16x8 g8(const void* base, size_t off) {
    if constexpr (!F32) {
        return *reinterpret_cast<const bf16x8*>((const __hip_bfloat16*)base + off);
    } else {
        const float* f = (const float*)base + off;
        float4 lo = *reinterpret_cast<const float4*>(f);
        float4 hi = *reinterpret_cast<const float4*>(f + 4);
        bf16x8 r;
        r[0] = (short)f2bs(lo.x); r[1] = (short)f2bs(lo.y);
        r[2] = (short)f2bs(lo.z); r[3] = (short)f2bs(lo.w);
        r[4] = (short)f2bs(hi.x); r[5] = (short)f2bs(hi.y);
        r[6] = (short)f2bs(hi.z); r[7] = (short)f2bs(hi.w);
        return r;
    }
}

template<bool F32>
__device__ __forceinline__ float ld1(const void* base, int i) {
    if constexpr (!F32) return bf2f(((const __hip_bfloat16*)base)[i]);
    else                return ((const float*)base)[i];
}

// ---------------- dtype detect: v1 (uniform[0.5,1.5]) ----------------
__global__ void detect_dtype(const void* v1) {
    const unsigned short* u = (const unsigned short*)v1;
    int f32 = 0;
    for (int i = 0; i < 8; ++i) {
        unsigned short s = u[i];
        __hip_bfloat16 h = *reinterpret_cast<__hip_bfloat16*>(&s);
        float v = __bfloat162float(h);
        if (!(v >= 0.25f && v <= 2.0f)) f32 = 1;
    }
    g_flag = f32;
}

// ---------------- weight pre-pack (fp32|bf16 -> bf16 fragment streams) ----------------
__device__ __forceinline__ unsigned short cvt1(const void* p, size_t i, bool f32) {
    if (f32) return f2bs(((const float*)p)[i]);
    return ((const unsigned short*)p)[i];
}

__global__ void prepack(const void* Wlin, const void* Wih, const void* Whh,
                        const void* Wc, const void* Wmu) {
    const bool f32 = (g_flag != 0);
    const int gid = blockIdx.x * 256 + threadIdx.x;
    const void* src;
    size_t dbase;
    int row, col0, ncols;
    if (gid < 24576) {                       // Whh [768,256]
        int idx = gid;
        int lane = idx & 63, j = (idx >> 6) & 1, kk = (idx >> 7) & 7;
        int t2 = idx >> 10, g = t2 % 3, w = t2 / 3;
        row = g * 256 + w * 32 + j * 16 + (lane & 15);
        col0 = kk * 32 + (lane >> 4) * 8;
        ncols = 256; src = Whh; dbase = WHH_E + (size_t)idx * 8;
    } else if (gid < 49152) {                // Wih [768,256]
        int idx = gid - 24576;
        int lane = idx & 63, j = (idx >> 6) & 1, kk = (idx >> 7) & 7;
        int t2 = idx >> 10, g = t2 % 3, w = t2 / 3;
        row = g * 256 + w * 32 + j * 16 + (lane & 15);
        col0 = kk * 32 + (lane >> 4) * 8;
        ncols = 256; src = Wih; dbase = WIH_E + (size_t)idx * 8;
    } else if (gid < 57344) {                // Wc [256,256]
        int idx = gid - 49152;
        int lane = idx & 63, j = (idx >> 6) & 1, kk = (idx >> 7) & 7, w = idx >> 10;
        row = w * 32 + j * 16 + (lane & 15);
        col0 = kk * 32 + (lane >> 4) * 8;
        ncols = 256; src = Wc; dbase = WC_E + (size_t)idx * 8;
    } else if (gid < 58368) {                // Wmu [32,256]
        int idx = gid - 57344;
        int lane = idx & 63, kk = (idx >> 6) & 7, w = idx >> 9;
        row = w * 16 + (lane & 15);
        col0 = kk * 32 + (lane >> 4) * 8;
        ncols = 256; src = Wmu; dbase = WMU_E + (size_t)idx * 8;
    } else if (gid < 78848) {                // Wlin [256,640]
        int idx = gid - 58368;
        int lane = idx & 63, j = (idx >> 6) & 1;
        int t1 = idx >> 7, kk = t1 % 20, w = t1 / 20;
        row = w * 32 + j * 16 + (lane & 15);
        col0 = kk * 32 + (lane >> 4) * 8;
        ncols = 640; src = Wlin; dbase = WLIN_E + (size_t)idx * 8;
    } else {
        return;
    }
    const size_t s0 = (size_t)row * ncols + col0;
    #pragma unroll
    for (int i = 0; i < 8; ++i) g_wpk[dbase + i] = cvt1(src, s0 + i, f32);
}

// ---------------- FAST PATH: BM=32, 512 threads, 8 waves, 1 barrier/step ----------------
template<bool F32>
__device__ __forceinline__ void fast_pipe(
    const void* hw, const void* blin,
    const void* g1, const void* be1, const void* m1, const void* v1, const void* a1,
    const void* bih, const void* bhh,
    const void* g2, const void* be2, const void* m2, const void* v2, const void* a2,
    const void* bc,
    const void* g3, const void* be3, const void* m3, const void* v3, const void* a3,
    const void* bmu,
    void* out,
    unsigned short (*hb)[BM * LDP],
    unsigned short (*yb)[BM * LDP],
    unsigned short (*zb)[BM * LDP])
{
    const int tid  = threadIdx.x;
    const int cg   = tid >> 6;        // wave = 32-col group, 0..7
    const int lane = tid & 63;
    const int m16  = lane & 15;
    const int q    = lane >> 4;
    const int row0 = blockIdx.x * BM;
    const int c0 = cg * 32 + m16;
    const int c1 = c0 + 16;
    const int cc2[2] = { c0, c1 };
    const size_t lane8 = (size_t)lane * 8;

    // persistent per-step params (folded)
    float s2v[2], t2v[2], s3v[2], t3f[2], bhhn[2];
    #pragma unroll
    for (int j = 0; j < 2; ++j) {
        const int cc = cc2[j];
        float s;
        s = ld1<F32>(g2, cc) * rsqrtf(ld1<F32>(v2, cc) + 1e-5f);
        s2v[j] = s; t2v[j] = ld1<F32>(be2, cc) - ld1<F32>(m2, cc) * s;
        s = ld1<F32>(g3, cc) * rsqrtf(ld1<F32>(v3, cc) + 1e-5f);
        s3v[j] = s;
        t3f[j] = (ld1<F32>(bc, cc) - ld1<F32>(m3, cc)) * s + ld1<F32>(be3, cc);
        bhhn[j] = ld1<F32>(bhh, 2 * H + cc);
    }
    const float a2v = ld1<F32>(a2, 0), a3v = ld1<F32>(a3, 0);

    // ---- Phase 1: x = prelu(bn1(rows @ Wlin^T + blin)) -> yb[0] ----
    {
        f32x4 xacc[2][2] = {};   // [mt][j]
        #pragma unroll 5
        for (int kk = 0; kk < F / 32; ++kk) {
            bf16x8 fa0 = g8<F32>(hw, (size_t)(row0 + m16) * F + kk * 32 + q * 8);
            bf16x8 fa1 = g8<F32>(hw, (size_t)(row0 + 16 + m16) * F + kk * 32 + q * 8);
            bf16x8 b0 = pk8(WLIN_E + (size_t)((cg * 20 + kk) * 2 + 0) * 512 + lane8);
            bf16x8 b1 = pk8(WLIN_E + (size_t)((cg * 20 + kk) * 2 + 1) * 512 + lane8);
            xacc[0][0] = MFMA16(fa0, b0, xacc[0][0]);
            xacc[1][0] = MFMA16(fa1, b0, xacc[1][0]);
            xacc[0][1] = MFMA16(fa0, b1, xacc[0][1]);
            xacc[1][1] = MFMA16(fa1, b1, xacc[1][1]);
        }
        #pragma unroll
        for (int j = 0; j < 2; ++j) {
            const int cc = cc2[j];
            float s = ld1<F32>(g1, cc) * rsqrtf(ld1<F32>(v1, cc) + 1e-5f);
            float t = ld1<F32>(be1, cc) - ld1<F32>(m1, cc) * s;
            float bl = ld1<F32>(blin, cc);
            float av = ld1<F32>(a1, 0);
            #pragma unroll
            for (int mt = 0; mt < 2; ++mt)
                #pragma unroll
                for (int r = 0; r < 4; ++r) {
                    float vv = (xacc[mt][j][r] + bl) * s + t;
                    vv = (vv >= 0.0f) ? vv : av * vv;
                    yb[0][(mt * 16 + q * 4 + r) * LDP + cc] = f2bs(vv);
                }
        }
    }
    __syncthreads();   // x visible in yb[0]

    // ---- Phase 2: gi = x @ Wih^T + biases; r/z packed bf16, n kept f32 ----
    unsigned girz[2][2][4];   // [mt][j][r]: lo = r-gate, hi = z-gate pre-act
    f32x4 gin[2][2];          // [mt][j]: n-gate pre-act
    {
        f32x4 ga[2][3][2] = {};
        const unsigned short* xa0 = yb[0] + m16 * LDP + q * 8;
        const unsigned short* xa1 = xa0 + 16 * LDP;
        #pragma unroll
        for (int kk = 0; kk < 8; ++kk) {
            bf16x8 fa0 = lds8(xa0 + kk * 32);
            bf16x8 fa1 = lds8(xa1 + kk * 32);
            #pragma unroll
            for (int g = 0; g < 3; ++g) {
                bf16x8 b0 = pk8(WIH_E + (size_t)(((cg * 3 + g) * 8 + kk) * 2 + 0) * 512 + lane8);
                bf16x8 b1 = pk8(WIH_E + (size_t)(((cg * 3 + g) * 8 + kk) * 2 + 1) * 512 + lane8);
                ga[0][g][0] = MFMA16(fa0, b0, ga[0][g][0]);
                ga[1][g][0] = MFMA16(fa1, b0, ga[1][g][0]);
                ga[0][g][1] = MFMA16(fa0, b1, ga[0][g][1]);
                ga[1][g][1] = MFMA16(fa1, b1, ga[1][g][1]);
            }
        }
        #pragma unroll
        for (int j = 0; j < 2; ++j) {
            const float br = ld1<F32>(bih, 0 * H + cc2[j]) + ld1<F32>(bhh, 0 * H + cc2[j]);
            const float bz = ld1<F32>(bih, 1 * H + cc2[j]) + ld1<F32>(bhh, 1 * H + cc2[j]);
            const float bn = ld1<F32>(bih, 2 * H + cc2[j]);
            #pragma unroll
            for (int mt = 0; mt < 2; ++mt) {
                #pragma unroll
                for (int r = 0; r < 4; ++r)
                    girz[mt][j][r] = pack2(ga[mt][0][j][r] + br, ga[mt][1][j][r] + bz);
                #pragma unroll
                for (int r = 0; r < 4; ++r) gin[mt][j][r] = ga[mt][2][j][r] + bn;
            }
        }
    }
    __syncthreads();   // protects yb[0] for reuse as y(0) at iter 0

    // ---- GRU loop, single barrier per iteration, Wc/Wmu pipelined ----
    // iter t: gh(t)<-hb[p]; gates -> hb[c],yb[c]
    //         Wc on y(t-1): yb[p] -> zb[p]
    //         Wmu on z(t-2): zb[c] -> out(t-2)
    // all cross-iteration hazards separated by the single end barrier.
    unsigned short hs[2][2][4];
    #pragma unroll
    for (int mt = 0; mt < 2; ++mt)
        #pragma unroll
        for (int j = 0; j < 2; ++j)
            #pragma unroll
            for (int r = 0; r < 4; ++r) hs[mt][j][r] = 0;   // bf16 +0.0

    const int mto = (cg >> 1) & 1;
    const int nto = cg & 1;
    const float bmuv = (cg < 4) ? ld1<F32>(bmu, nto * 16 + m16) : 0.0f;

    #pragma unroll 1
    for (int t = 0; t < LSTEPS + 2; ++t) {
        const int cur = t & 1, prv = cur ^ 1;

        // --- recurrence: gh(t) + gates -> hb[cur], yb[cur] ---
        if (t < LSTEPS) {
            f32x4 gh[2][3][2] = {};
            if (t > 0) {
                const unsigned short* ha0 = hb[prv] + m16 * LDP + q * 8;
                const unsigned short* ha1 = ha0 + 16 * LDP;
                #pragma unroll
                for (int kk = 0; kk < 8; ++kk) {
                    bf16x8 fa0 = lds8(ha0 + kk * 32);
                    bf16x8 fa1 = lds8(ha1 + kk * 32);
                    #pragma unroll
                    for (int g = 0; g < 3; ++g) {
                        bf16x8 b0 = pk8(WHH_E + (size_t)(((cg * 3 + g) * 8 + kk) * 2 + 0) * 512 + lane8);
                        bf16x8 b1 = pk8(WHH_E + (size_t)(((cg * 3 + g) * 8 + kk) * 2 + 1) * 512 + lane8);
                        gh[0][g][0] = MFMA16(fa0, b0, gh[0][g][0]);
                        gh[1][g][0] = MFMA16(fa1, b0, gh[1][g][0]);
                        gh[0][g][1] = MFMA16(fa0, b1, gh[0][g][1]);
                        gh[1][g][1] = MFMA16(fa1, b1, gh[1][g][1]);
                    }
                }
            }
            #pragma unroll
            for (int mt = 0; mt < 2; ++mt)
                #pragma unroll
                for (int j = 0; j < 2; ++j)
                    #pragma unroll
                    for (int r = 0; r < 4; ++r) {
                        unsigned u = girz[mt][j][r];
                        float rr = sigm(bfu((unsigned short)(u & 0xffffu)) + gh[mt][0][j][r]);
                        float zz = sigm(bfu((unsigned short)(u >> 16)) + gh[mt][1][j][r]);
                        float nin = gin[mt][j][r] + rr * (gh[mt][2][j][r] + bhhn[j]);
                        float nn = 2.0f * sigm(2.0f * nin) - 1.0f;   // tanh
                        float hh = (1.0f - zz) * nn + zz * bfu(hs[mt][j][r]);
                        unsigned short hv = f2bs(hh);
                        hs[mt][j][r] = hv;
                        const int idx = (mt * 16 + q * 4 + r) * LDP + cc2[j];
                        hb[cur][idx] = hv;
                        float y = bfu(hv) * s2v[j] + t2v[j];
                        y = (y >= 0.0f) ? y : a2v * y;
                        yb[cur][idx] = f2bs(y);
                    }
        }

        // --- Wc on y(t-1): yb[prv] -> z -> zb[prv] ---
        if (t >= 1 && t <= LSTEPS) {
            f32x4 w2[2][2] = {};
            const unsigned short* ya0 = yb[prv] + m16 * LDP + q * 8;
            const unsigned short* ya1 = ya0 + 16 * LDP;
            #pragma unroll
            for (int kk = 0; kk < 8; ++kk) {
                bf16x8 fa0 = lds8(ya0 + kk * 32);
                bf16x8 fa1 = lds8(ya1 + kk * 32);
                bf16x8 b0 = pk8(WC_E + (size_t)((cg * 8 + kk) * 2 + 0) * 512 + lane8);
                bf16x8 b1 = pk8(WC_E + (size_t)((cg * 8 + kk) * 2 + 1) * 512 + lane8);
                w2[0][0] = MFMA16(fa0, b0, w2[0][0]);
                w2[1][0] = MFMA16(fa1, b0, w2[1][0]);
                w2[0][1] = MFMA16(fa0, b1, w2[0][1]);
                w2[1][1] = MFMA16(fa1, b1, w2[1][1]);
            }
            #pragma unroll
            for (int mt = 0; mt < 2; ++mt)
                #pragma unroll
                for (int j = 0; j < 2; ++j)
                    #pragma unroll
                    for (int r = 0; r < 4; ++r) {
                        float z0 = w2[mt][j][r] * s3v[j] + t3f[j];
                        z0 = (z0 >= 0.0f) ? z0 : a3v * z0;
                        zb[prv][(mt * 16 + q * 4 + r) * LDP + cc2[j]] = f2bs(z0);
                    }
        }

        // --- Wmu on z(t-2): zb[cur] -> out(t-2) ---
        if (t >= 2 && cg < 4) {
            const int ts = t - 2;
            const unsigned short* za = zb[cur] + (mto * 16 + m16) * LDP + q * 8;
            f32x4 o = {};
            #pragma unroll
            for (int kk = 0; kk < 8; ++kk) {
                bf16x8 a = lds8(za + kk * 32);
                bf16x8 b = pk8(WMU_E + (size_t)(nto * 8 + kk) * 512 + lane8);
                o = MFMA16(a, b, o);
            }
            #pragma unroll
            for (int r = 0; r < 4; ++r) {
                float vv = o[r] + bmuv;
                const size_t oi = (size_t)(row0 + mto * 16 + q * 4 + r) * (LSTEPS * CO)
                                + ts * CO + nto * 16 + m16;
                if constexpr (F32) ((float*)out)[oi] = vv;
                else               ((__hip_bfloat16*)out)[oi] = __float2bfloat16(vv);
            }
        }

        if (t < LSTEPS + 1) __syncthreads();   // the ONLY barrier per step
    }
}

__global__ __launch_bounds__(512, 2) void comm_fast(
    const void* hw, const void* blin,
    const void* g1, const void* be1, const void* m1, const void* v1, const void* a1,
    const void* bih, const void* bhh,
    const void* g2, const void* be2, const void* m2, const void* v2, const void* a2,
    const void* bc,
    const void* g3, const void* be3, const void* m3, const void* v3, const void* a3,
    const void* bmu,
    void* out)
{
    __shared__ __align__(16) unsigned short hb[2][BM * LDP];
    __shared__ __align__(16) unsigned short yb[2][BM * LDP];
    __shared__ __align__(16) unsigned short zb[2][BM * LDP];
    if (g_flag) {
        fast_pipe<true >(hw, blin, g1, be1, m1, v1, a1, bih, bhh,
                         g2, be2, m2, v2, a2, bc, g3, be3, m3, v3, a3, bmu,
                         out, hb, yb, zb);
    } else {
        fast_pipe<false>(hw, blin, g1, be1, m1, v1, a1, bih, bhh,
                         g2, be2, m2, v2, a2, bc, g3, be3, m3, v3, a3, bmu,
                         out, hb, yb, zb);
    }
}

extern "C" void kernel_launch(void* const* d_in, const int* in_sizes, int n_in,
                              void* d_out, int out_size, void* d_ws, size_t ws_size,
                              hipStream_t stream) {
    (void)in_sizes; (void)n_in; (void)out_size; (void)d_ws; (void)ws_size;
    detect_dtype<<<dim3(1), dim3(1), 0, stream>>>(d_in[6]);
    prepack<<<dim3(308), dim3(256), 0, stream>>>(
        d_in[1], d_in[8], d_in[9], d_in[17], d_in[24]);
    comm_fast<<<dim3(256), dim3(512), 0, stream>>>(
        d_in[0], d_in[2],
        d_in[3], d_in[4], d_in[5], d_in[6], d_in[7],
        d_in[10], d_in[11],
        d_in[12], d_in[13], d_in[14], d_in[15], d_in[16],
        d_in[18],
        d_in[19], d_in[20], d_in[21], d_in[22], d_in[23],
        d_in[25],
        d_out);
}